// Round 1
// baseline (2721.823 us; speedup 1.0000x reference)
//
#include <hip/hip_runtime.h>

// DCGRU cell, MI355X gfx950.
// Sizes (hardcoded from reference): N=4096 nodes, B=64 batch, IN_DIM=2,
// UNITS=64, K=2, NSUP=2, M=5, IN_SZ=66, CB = IN_SZ*B = 4224.
//
// Heavy work: 8x GEMM  Y(4096 x 4224) = S(4096x4096) @ X(4096x4224), bf16 MFMA.
// All X/Y matrices stored TRANSPOSED (XT[col][k], 4224 x 4096) so both MFMA
// operands read k-contiguous 16B fragments from LDS.

typedef unsigned short u16;
typedef __attribute__((ext_vector_type(8))) short short8;   // bf16x8 MFMA frag
typedef __attribute__((ext_vector_type(4))) float floatx4;  // MFMA acc
typedef __attribute__((ext_vector_type(4))) u16 u16x4;

__device__ __forceinline__ u16 f2b(float f) {            // fp32 -> bf16 RNE
    unsigned int x = __float_as_uint(f);
    return (u16)((x + 0x7fffu + ((x >> 16) & 1u)) >> 16);
}
__device__ __forceinline__ float b2f(u16 u) {
    return __uint_as_float(((unsigned int)u) << 16);
}

// ---------------------------------------------------------------- cvt fp32->bf16
__global__ void cvt_bf16_kernel(const float* __restrict__ src, u16* __restrict__ dst) {
    size_t i = ((size_t)blockIdx.x * 256 + threadIdx.x) * 4;
    floatx4 v = *(const floatx4*)&src[i];
    u16x4 p; p[0] = f2b(v[0]); p[1] = f2b(v[1]); p[2] = f2b(v[2]); p[3] = f2b(v[3]);
    *(u16x4*)&dst[i] = p;
}

// ------------------------------------------- x0T rows 0..127  (c=0,1 from inputs)
// x0T[(c*64+b)][n] = inputs[b][n*2+c]
__global__ void build_x0_inputs(const float* __restrict__ inp, u16* __restrict__ x0T) {
    const int row = blockIdx.x;           // 0..127
    const int c = row >> 6, b = row & 63;
    const int t = threadIdx.x;
    const int n0 = t * 16;
    u16* dst = x0T + (size_t)row * 4096 + n0;
    #pragma unroll
    for (int g = 0; g < 4; ++g) {
        u16x4 pk;
        #pragma unroll
        for (int e = 0; e < 4; ++e) {
            const float* p = &inp[(size_t)b * 8192 + (size_t)(n0 + g * 4 + e) * 2];
            pk[e] = f2b(c ? p[1] : p[0]);
        }
        *(u16x4*)(dst + g * 4) = pk;
    }
}

// ----------------------------- x0T rows 128..4223 from state (hx):  transpose
// x0T[(j+2)*64+b][n] = state[b][n*64+j]
__global__ void build_x0_state(const float* __restrict__ st, u16* __restrict__ x0T) {
    __shared__ float lds[64 * 68];
    const int t = threadIdx.x;
    const int n0 = blockIdx.x * 64, b = blockIdx.y;
    const float* src = st + (size_t)b * 262144 + (size_t)n0 * 64;
    #pragma unroll
    for (int r = 0; r < 4; ++r) {
        int i = r * 1024 + t * 4;                 // contiguous 16KB read
        floatx4 v = *(const floatx4*)&src[i];
        int nl = i >> 6, j = i & 63;              // j%4==0 -> aligned LDS float4
        *(floatx4*)&lds[nl * 68 + j] = v;
    }
    __syncthreads();
    const int j = t >> 2, q = t & 3;
    u16* dst = x0T + (size_t)((j + 2) * 64 + b) * 4096 + n0 + q * 16;
    #pragma unroll
    for (int g = 0; g < 4; ++g) {
        u16x4 pk;
        #pragma unroll
        for (int e = 0; e < 4; ++e) pk[e] = f2b(lds[(q * 16 + g * 4 + e) * 68 + j]);
        *(u16x4*)(dst + g * 4) = pk;
    }
}

// --------------------------------------------------------------- bf16 MFMA GEMM
// C[m][col] = sum_k A[m][k] * XT[col][k];  store YT[col][m] (bf16)
// EPI==1: Y = 2*C - Z  (Z in same transposed bf16 layout)
template <int EPI>
__global__ __launch_bounds__(256, 2) void gemm_kernel(
        const u16* __restrict__ A, const u16* __restrict__ B,
        u16* __restrict__ Y, const u16* __restrict__ Z) {
    __shared__ __align__(16) u16 As[128 * 32];
    __shared__ __align__(16) u16 Bs[128 * 32];
    const int t = threadIdx.x;
    const int lane = t & 63, wave = t >> 6;
    const int m16 = lane & 15, quad = lane >> 4;
    const int wr = wave >> 1, wc = wave & 1;
    const int rb = blockIdx.x, cb = blockIdx.y;

    const u16* aG = A + (size_t)(rb * 128 + (t >> 2)) * 4096 + (t & 3) * 8;
    const u16* bG = B + (size_t)(cb * 128 + (t >> 2)) * 4096 + (t & 3) * 8;
    const int ldsOff = (t >> 2) * 32 + (t & 3) * 8;

    floatx4 acc[4][4];
    #pragma unroll
    for (int i = 0; i < 4; ++i)
        #pragma unroll
        for (int j = 0; j < 4; ++j) acc[i][j] = (floatx4)0.f;

    for (int kt = 0; kt < 128; ++kt) {
        __syncthreads();
        *(int4*)&As[ldsOff]           = *(const int4*)aG;
        *(int4*)&As[ldsOff + 64 * 32] = *(const int4*)(aG + (size_t)64 * 4096);
        *(int4*)&Bs[ldsOff]           = *(const int4*)bG;
        *(int4*)&Bs[ldsOff + 64 * 32] = *(const int4*)(bG + (size_t)64 * 4096);
        aG += 32; bG += 32;
        __syncthreads();
        short8 af[4], bf[4];
        #pragma unroll
        for (int i = 0; i < 4; ++i)
            af[i] = *(const short8*)&As[(wr * 64 + i * 16 + m16) * 32 + quad * 8];
        #pragma unroll
        for (int j = 0; j < 4; ++j)
            bf[j] = *(const short8*)&Bs[(wc * 64 + j * 16 + m16) * 32 + quad * 8];
        #pragma unroll
        for (int i = 0; i < 4; ++i)
            #pragma unroll
            for (int j = 0; j < 4; ++j)
                acc[i][j] = __builtin_amdgcn_mfma_f32_16x16x32_bf16(af[i], bf[j], acc[i][j], 0, 0, 0);
    }
    #pragma unroll
    for (int i = 0; i < 4; ++i) {
        const int row = rb * 128 + wr * 64 + i * 16 + quad * 4;
        #pragma unroll
        for (int j = 0; j < 4; ++j) {
            const int col = cb * 128 + wc * 64 + j * 16 + m16;
            const size_t off = (size_t)col * 4096 + row;
            floatx4 v = acc[i][j];
            if (EPI) {
                u16x4 z = *(const u16x4*)(Z + off);
                #pragma unroll
                for (int e = 0; e < 4; ++e) v[e] = 2.f * v[e] - b2f(z[e]);
            }
            u16x4 pk;
            #pragma unroll
            for (int e = 0; e < 4; ++e) pk[e] = f2b(v[e]);
            *(u16x4*)(Y + off) = pk;
        }
    }
}

// ------------------------------------------------- projection fn + gate fusion
// value[bn][o] = sigmoid( sum_{c,m} xsT[m][c*64+b][n] * W[c*5+m][o] + bias[o] )
// o<64  : r  -> x0T[(o+2)*64+b][n] = bf16(r * hx[b][n*64+o])   (state for gconv2)
// o>=64 : u  -> u_t[(o-64)*64+b][n] (fp32)
__global__ __launch_bounds__(256) void proj_fn_kernel(
        const u16* __restrict__ x0T, const u16* __restrict__ y1T,
        const u16* __restrict__ y2T, const u16* __restrict__ y3T,
        const u16* __restrict__ y4T,
        const float* __restrict__ W, const float* __restrict__ bias,
        const float* __restrict__ hx,
        float* __restrict__ u_t, u16* __restrict__ x0Tw) {
    __shared__ __align__(16) u16 xls[330 * 32];   // 21120 B
    __shared__ __align__(16) u16 wls[165 * 128];  // 42240 B
    const int t = threadIdx.x;
    const int n0 = blockIdx.x * 32, b = blockIdx.y;
    {
        const u16* xs0[5] = {x0T, y1T, y2T, y3T, y4T};
        for (int r = t; r < 330; r += 256) {
            int c = r / 5, m = r - c * 5;
            const int4* s4 = (const int4*)(xs0[m] + (size_t)(c * 64 + b) * 4096 + n0);
            int4* d4 = (int4*)&xls[r * 32];
            d4[0] = s4[0]; d4[1] = s4[1]; d4[2] = s4[2]; d4[3] = s4[3];
        }
    }
    const int og = t & 31, ng = t >> 5;   // o = og*4+a (0..127), n = n0+ng*4+d (32 wide)
    float acc[4][4] = {};
    for (int ch = 0; ch < 2; ++ch) {
        __syncthreads();
        for (int i = t; i < 165 * 128; i += 256) wls[i] = f2b(W[ch * (165 * 128) + i]);
        __syncthreads();
        for (int cl = 0; cl < 165; ++cl) {
            const int cm = ch * 165 + cl;
            u16x4 xr = *(const u16x4*)&xls[cm * 32 + ng * 4];
            u16x4 wv4 = *(const u16x4*)&wls[cl * 128 + og * 4];
            float xv[4], wv[4];
            #pragma unroll
            for (int e = 0; e < 4; ++e) { xv[e] = b2f(xr[e]); wv[e] = b2f(wv4[e]); }
            #pragma unroll
            for (int a = 0; a < 4; ++a)
                #pragma unroll
                for (int d = 0; d < 4; ++d) acc[a][d] += wv[a] * xv[d];
        }
    }
    const int o0 = og * 4;
    float s[4][4];
    #pragma unroll
    for (int a = 0; a < 4; ++a) {
        const float bo = bias[o0 + a];
        #pragma unroll
        for (int d = 0; d < 4; ++d) s[a][d] = 1.f / (1.f + __expf(-(acc[a][d] + bo)));
    }
    if (o0 < 64) {        // r part -> new state rows of x0T
        float h[4][4];
        #pragma unroll
        for (int d = 0; d < 4; ++d) {
            floatx4 hv = *(const floatx4*)&hx[(size_t)b * 262144 + (size_t)(n0 + ng * 4 + d) * 64 + o0];
            #pragma unroll
            for (int a = 0; a < 4; ++a) h[d][a] = hv[a];
        }
        #pragma unroll
        for (int a = 0; a < 4; ++a) {
            u16x4 pk;
            #pragma unroll
            for (int d = 0; d < 4; ++d) pk[d] = f2b(s[a][d] * h[d][a]);
            *(u16x4*)(x0Tw + (size_t)((o0 + a + 2) * 64 + b) * 4096 + n0 + ng * 4) = pk;
        }
    } else {              // u part
        #pragma unroll
        for (int a = 0; a < 4; ++a) {
            floatx4 uv;
            #pragma unroll
            for (int d = 0; d < 4; ++d) uv[d] = s[a][d];
            *(floatx4*)(u_t + (size_t)((o0 + a - 64) * 64 + b) * 4096 + n0 + ng * 4) = uv;
        }
    }
}

// ------------------------------------- projection g + tanh + GRU output fusion
// c = tanh(gconv_g);  out[b][n*64+o] = u*hx + (1-u)*c
__global__ __launch_bounds__(256) void proj_g_kernel(
        const u16* __restrict__ x0T, const u16* __restrict__ y1T,
        const u16* __restrict__ y2T, const u16* __restrict__ y3T,
        const u16* __restrict__ y4T,
        const float* __restrict__ W, const float* __restrict__ bias,
        const float* __restrict__ hx, const float* __restrict__ u_t,
        float* __restrict__ out) {
    __shared__ __align__(16) u16 xls[330 * 64];  // 42240 B
    __shared__ __align__(16) u16 wls[165 * 64];  // 21120 B
    const int t = threadIdx.x;
    const int n0 = blockIdx.x * 64, b = blockIdx.y;
    {
        const u16* xs0[5] = {x0T, y1T, y2T, y3T, y4T};
        for (int r = t; r < 330; r += 256) {
            int c = r / 5, m = r - c * 5;
            const int4* s4 = (const int4*)(xs0[m] + (size_t)(c * 64 + b) * 4096 + n0);
            int4* d4 = (int4*)&xls[r * 64];
            #pragma unroll
            for (int e = 0; e < 8; ++e) d4[e] = s4[e];
        }
    }
    const int og = t & 15, ng = t >> 4;   // o = og*4+a (0..63), n = n0+ng*4+d (64 wide)
    float acc[4][4] = {};
    for (int ch = 0; ch < 2; ++ch) {
        __syncthreads();
        for (int i = t; i < 165 * 64; i += 256) wls[i] = f2b(W[ch * (165 * 64) + i]);
        __syncthreads();
        for (int cl = 0; cl < 165; ++cl) {
            const int cm = ch * 165 + cl;
            u16x4 xr = *(const u16x4*)&xls[cm * 64 + ng * 4];
            u16x4 wv4 = *(const u16x4*)&wls[cl * 64 + og * 4];
            float xv[4], wv[4];
            #pragma unroll
            for (int e = 0; e < 4; ++e) { xv[e] = b2f(xr[e]); wv[e] = b2f(wv4[e]); }
            #pragma unroll
            for (int a = 0; a < 4; ++a)
                #pragma unroll
                for (int d = 0; d < 4; ++d) acc[a][d] += wv[a] * xv[d];
        }
    }
    const int o0 = og * 4;
    float cg[4][4], h[4][4], u[4][4];
    #pragma unroll
    for (int a = 0; a < 4; ++a) {
        const float bo = bias[o0 + a];
        #pragma unroll
        for (int d = 0; d < 4; ++d) cg[a][d] = tanhf(acc[a][d] + bo);
    }
    #pragma unroll
    for (int d = 0; d < 4; ++d) {
        floatx4 hv = *(const floatx4*)&hx[(size_t)b * 262144 + (size_t)(n0 + ng * 4 + d) * 64 + o0];
        #pragma unroll
        for (int a = 0; a < 4; ++a) h[d][a] = hv[a];
    }
    #pragma unroll
    for (int a = 0; a < 4; ++a) {
        floatx4 uv = *(const floatx4*)&u_t[(size_t)((o0 + a) * 64 + b) * 4096 + n0 + ng * 4];
        #pragma unroll
        for (int d = 0; d < 4; ++d) u[a][d] = uv[d];
    }
    #pragma unroll
    for (int d = 0; d < 4; ++d) {
        floatx4 ov;
        #pragma unroll
        for (int a = 0; a < 4; ++a) ov[a] = u[a][d] * h[d][a] + (1.f - u[a][d]) * cg[a][d];
        *(floatx4*)&out[(size_t)b * 262144 + (size_t)(n0 + ng * 4 + d) * 64 + o0] = ov;
    }
}

// --------------------------------------------------------------------- launch
extern "C" void kernel_launch(void* const* d_in, const int* in_sizes, int n_in,
                              void* d_out, int out_size, void* d_ws, size_t ws_size,
                              hipStream_t stream) {
    (void)in_sizes; (void)n_in; (void)out_size; (void)ws_size;
    const float* inputs   = (const float*)d_in[0];
    const float* hx       = (const float*)d_in[1];
    const float* supports = (const float*)d_in[2];
    const float* w_fn     = (const float*)d_in[3];
    const float* b_fn     = (const float*)d_in[4];
    const float* w_g      = (const float*)d_in[5];
    const float* b_g      = (const float*)d_in[6];
    float* out = (float*)d_out;

    const size_t NN = (size_t)4096 * 4096;      // 16.78M
    const size_t XT = (size_t)4224 * 4096;      // 17.30M
    u16* Sb  = (u16*)d_ws;                      // S0b,S1b bf16       (67.1 MB)
    u16* x0T = Sb + 2 * NN;                     // x0 transposed bf16 (34.6 MB)
    u16* y1T = x0T + XT;
    u16* y2T = y1T + XT;
    u16* y3T = y2T + XT;
    u16* y4T = y3T + XT;
    float* u_t = (float*)(y4T + XT);            // u gate fp32        (67.1 MB)
    u16* S0b = Sb;
    u16* S1b = Sb + NN;

    const dim3 gg(32, 33);   // 4096/128 x 4224/128

    cvt_bf16_kernel<<<32768, 256, 0, stream>>>(supports, Sb);
    build_x0_inputs<<<128, 256, 0, stream>>>(inputs, x0T);
    build_x0_state<<<dim3(64, 64), 256, 0, stream>>>(hx, x0T);
    // gconv fn diffusion
    gemm_kernel<0><<<gg, 256, 0, stream>>>(S0b, x0T, y1T, nullptr);
    gemm_kernel<1><<<gg, 256, 0, stream>>>(S0b, y1T, y2T, x0T);
    gemm_kernel<0><<<gg, 256, 0, stream>>>(S1b, y1T, y3T, nullptr);
    gemm_kernel<1><<<gg, 256, 0, stream>>>(S1b, y3T, y4T, y1T);
    // r,u gates; writes r*hx into x0T state rows + u into u_t
    proj_fn_kernel<<<dim3(128, 64), 256, 0, stream>>>(x0T, y1T, y2T, y3T, y4T,
                                                      w_fn, b_fn, hx, u_t, x0T);
    // gconv g diffusion (x0T now holds [inputs, r*hx])
    gemm_kernel<0><<<gg, 256, 0, stream>>>(S0b, x0T, y1T, nullptr);
    gemm_kernel<1><<<gg, 256, 0, stream>>>(S0b, y1T, y2T, x0T);
    gemm_kernel<0><<<gg, 256, 0, stream>>>(S1b, y1T, y3T, nullptr);
    gemm_kernel<1><<<gg, 256, 0, stream>>>(S1b, y3T, y4T, y1T);
    // c = tanh(...), out = u*hx + (1-u)*c
    proj_g_kernel<<<dim3(64, 64), 256, 0, stream>>>(x0T, y1T, y2T, y3T, y4T,
                                                    w_g, b_g, hx, u_t, out);
}

// Round 2
// 2118.504 us; speedup vs baseline: 1.2848x; 1.2848x over previous
//
#include <hip/hip_runtime.h>

// DCGRU cell, MI355X gfx950.  N=4096, B=64, IN_DIM=2, UNITS=64, K=2, NSUP=2,
// M=5, IN_SZ=66.  Heavy: 8x GEMM Y(4096x4224)=S(4096x4096)@X, bf16 MFMA with
// global_load_lds staging (m97 structure).  Projections are MFMA GEMMs over
// K=330 (pad 384) with k-pair-interleaved LDS staging of X.

typedef unsigned short u16;
typedef unsigned int u32;
typedef __attribute__((ext_vector_type(8))) short short8;   // bf16x8 MFMA frag
typedef __attribute__((ext_vector_type(4))) float floatx4;  // MFMA acc
typedef __attribute__((ext_vector_type(4))) u16 u16x4;

__device__ __forceinline__ u16 f2b(float f) {            // fp32 -> bf16 RNE
    u32 x = __float_as_uint(f);
    return (u16)((x + 0x7fffu + ((x >> 16) & 1u)) >> 16);
}
__device__ __forceinline__ float b2f(u16 u) {
    return __uint_as_float(((u32)u) << 16);
}

// async global->LDS, 16B per lane; LDS dest = wave-uniform base + lane*16
#define GLL16(g, l) __builtin_amdgcn_global_load_lds( \
    (const __attribute__((address_space(1))) void*)(g), \
    (__attribute__((address_space(3))) void*)(l), 16, 0, 0)

// ---------------------------------------------------------------- cvt fp32->bf16
__global__ void cvt_bf16_kernel(const float* __restrict__ src, u16* __restrict__ dst) {
    size_t i = ((size_t)blockIdx.x * 256 + threadIdx.x) * 4;
    floatx4 v = *(const floatx4*)&src[i];
    u16x4 p; p[0] = f2b(v[0]); p[1] = f2b(v[1]); p[2] = f2b(v[2]); p[3] = f2b(v[3]);
    *(u16x4*)&dst[i] = p;
}

// ------------------------------------------- x0T rows 0..127  (c=0,1 from inputs)
__global__ void build_x0_inputs(const float* __restrict__ inp, u16* __restrict__ x0T) {
    const int row = blockIdx.x;           // 0..127
    const int c = row >> 6, b = row & 63;
    const int t = threadIdx.x;
    const int n0 = t * 16;
    u16* dst = x0T + (size_t)row * 4096 + n0;
    #pragma unroll
    for (int g = 0; g < 4; ++g) {
        u16x4 pk;
        #pragma unroll
        for (int e = 0; e < 4; ++e) {
            const float* p = &inp[(size_t)b * 8192 + (size_t)(n0 + g * 4 + e) * 2];
            pk[e] = f2b(c ? p[1] : p[0]);
        }
        *(u16x4*)(dst + g * 4) = pk;
    }
}

// ----------------------------- x0T rows 128..4223 from state (hx):  transpose
__global__ void build_x0_state(const float* __restrict__ st, u16* __restrict__ x0T) {
    __shared__ float lds[64 * 68];
    const int t = threadIdx.x;
    const int n0 = blockIdx.x * 64, b = blockIdx.y;
    const float* src = st + (size_t)b * 262144 + (size_t)n0 * 64;
    #pragma unroll
    for (int r = 0; r < 4; ++r) {
        int i = r * 1024 + t * 4;
        floatx4 v = *(const floatx4*)&src[i];
        int nl = i >> 6, j = i & 63;
        *(floatx4*)&lds[nl * 68 + j] = v;
    }
    __syncthreads();
    const int j = t >> 2, q = t & 3;
    u16* dst = x0T + (size_t)((j + 2) * 64 + b) * 4096 + n0 + q * 16;
    #pragma unroll
    for (int g = 0; g < 4; ++g) {
        u16x4 pk;
        #pragma unroll
        for (int e = 0; e < 4; ++e) pk[e] = f2b(lds[(q * 16 + g * 4 + e) * 68 + j]);
        *(u16x4*)(dst + g * 4) = pk;
    }
}

// -------------------------------------------- W^T prep: WT[o][k] bf16, k pad 384
__global__ void wt_prep(const float* __restrict__ W, u16* __restrict__ WT, int O) {
    int idx = blockIdx.x * 256 + threadIdx.x;   // o*384 + k
    int o = idx / 384, k = idx - o * 384;
    if (o < O) WT[idx] = (k < 330) ? f2b(W[(size_t)k * O + o]) : (u16)0;
}

// --------------------------------------------------------------- bf16 MFMA GEMM
// C[m][col] = sum_k A[m][k]*XT[col][k]; store YT[col][m].  EPI: Y = 2*C - Z.
template <int EPI>
__global__ __launch_bounds__(256, 2) void gemm_kernel(
        const u16* __restrict__ A, const u16* __restrict__ B,
        u16* __restrict__ Y, const u16* __restrict__ Z) {
    __shared__ __align__(16) u16 As[128 * 32];   // unpadded: global_load_lds layout
    __shared__ __align__(16) u16 Bs[128 * 32];
    const int t = threadIdx.x;
    const int lane = t & 63, wave = t >> 6;
    const int m16 = lane & 15, quad = lane >> 4;
    const int wr = wave >> 1, wc = wave & 1;
    const int rb = blockIdx.x, cb = blockIdx.y;

    // staging: wave w covers rows w*32..w*32+31; one instr = 16 rows (64 lanes x 16B)
    const int r0 = wave * 32 + (lane >> 2);
    const int sg = lane & 3;
    const u16* aG = A + (size_t)(rb * 128 + r0) * 4096 + sg * 8;
    const u16* bG = B + (size_t)(cb * 128 + r0) * 4096 + sg * 8;
    u16* aL = As + wave * 1024;   // wave-uniform LDS base
    u16* bL = Bs + wave * 1024;

    floatx4 acc[4][4];
    #pragma unroll
    for (int i = 0; i < 4; ++i)
        #pragma unroll
        for (int j = 0; j < 4; ++j) acc[i][j] = (floatx4)0.f;

    for (int kt = 0; kt < 128; ++kt) {
        __syncthreads();
        GLL16(aG, aL);
        GLL16(aG + (size_t)16 * 4096, aL + 512);
        GLL16(bG, bL);
        GLL16(bG + (size_t)16 * 4096, bL + 512);
        aG += 32; bG += 32;
        __syncthreads();   // drains vmcnt -> staged data visible
        short8 af[4], bf[4];
        #pragma unroll
        for (int i = 0; i < 4; ++i)
            af[i] = *(const short8*)&As[(wr * 64 + i * 16 + m16) * 32 + quad * 8];
        #pragma unroll
        for (int j = 0; j < 4; ++j)
            bf[j] = *(const short8*)&Bs[(wc * 64 + j * 16 + m16) * 32 + quad * 8];
        #pragma unroll
        for (int i = 0; i < 4; ++i)
            #pragma unroll
            for (int j = 0; j < 4; ++j)
                acc[i][j] = __builtin_amdgcn_mfma_f32_16x16x32_bf16(af[i], bf[j], acc[i][j], 0, 0, 0);
    }
    #pragma unroll
    for (int i = 0; i < 4; ++i) {
        const int row = rb * 128 + wr * 64 + i * 16 + quad * 4;
        #pragma unroll
        for (int j = 0; j < 4; ++j) {
            const int col = cb * 128 + wc * 64 + j * 16 + m16;
            const size_t off = (size_t)col * 4096 + row;
            floatx4 v = acc[i][j];
            if (EPI) {
                u16x4 z = *(const u16x4*)(Z + off);
                #pragma unroll
                for (int e = 0; e < 4; ++e) v[e] = 2.f * v[e] - b2f(z[e]);
            }
            u16x4 pk;
            #pragma unroll
            for (int e = 0; e < 4; ++e) pk[e] = f2b(v[e]);
            *(u16x4*)(Y + off) = pk;
        }
    }
}

// --------------------------------------------------------- proj helpers (X rows)
__device__ __forceinline__ const u16* xrow(int k, int b,
        const u16* x0, const u16* y1, const u16* y2, const u16* y3, const u16* y4) {
    int c = (int)((unsigned)k / 5u);
    int m = k - c * 5;
    if (c > 65) c = 65;                       // pad region: clamp in-bounds (W=0 there)
    const u16* base = (m == 0) ? x0 : (m == 1) ? y1 : (m == 2) ? y2 : (m == 3) ? y3 : y4;
    return base + (size_t)(c * 64 + b) * 4096;
}

__device__ __forceinline__ void ilv(uint4 a, uint4 b, u32* w) {
    // a = 8 bf16 of row k, b = 8 bf16 of row k+1 -> 8 words (k|k+1<<16) per bn
    const u32* ap = (const u32*)&a; const u32* bp = (const u32*)&b;
    #pragma unroll
    for (int i = 0; i < 4; ++i) {
        u32 x = ap[i], y = bp[i];
        w[2 * i]     = (x & 0xffffu) | (y << 16);
        w[2 * i + 1] = (x >> 16) | (y & 0xffff0000u);
    }
}

// ------------------------------------------------- proj fn: MFMA GEMM + gates
// D[o][bn] = sum_k WT[o][k] * X[k][bn];  sigmoid; o<64: r -> x0T state rows
// (r*hx, bf16, in-place safe: block (b,n-tile) reads only its own region);
// o>=64: u -> u_t[bn*64+o'] bf16.
__global__ __launch_bounds__(256, 2) void proj_fn_kernel(
        const u16* __restrict__ x0T, const u16* __restrict__ y1T,
        const u16* __restrict__ y2T, const u16* __restrict__ y3T,
        const u16* __restrict__ y4T,
        const u16* __restrict__ WT, const float* __restrict__ bias,
        const float* __restrict__ hx,
        u16* __restrict__ u_t, u16* __restrict__ x0Tw) {
    __shared__ __align__(16) u32 Xs[32 * 132];   // [kp][bn] interleaved, 16.9 KB
    __shared__ __align__(16) u16 Ws[128 * 72];   // [o][k] pad 72, 18.4 KB
    const int t = threadIdx.x;
    const int lane = t & 63, wave = t >> 6;
    const int m16 = lane & 15, quad = lane >> 4;
    const int wr = wave >> 1, wc = wave & 1;
    const int n0 = blockIdx.x * 128, b = blockIdx.y;

    const int kp = t >> 3, sgx = t & 7;          // X staging: kp 0..31, 16 n per sgx
    const int wrow = t >> 1, whalf = t & 1;      // W staging

    floatx4 acc[4][4];
    #pragma unroll
    for (int i = 0; i < 4; ++i)
        #pragma unroll
        for (int j = 0; j < 4; ++j) acc[i][j] = (floatx4)0.f;

    for (int ki = 0; ki < 6; ++ki) {
        const int k0 = ki * 64;
        // issue global loads first (overlap with prior compute wind-down)
        const u16* pa = xrow(k0 + 2 * kp,     b, x0T, y1T, y2T, y3T, y4T) + n0 + sgx * 16;
        const u16* pb = xrow(k0 + 2 * kp + 1, b, x0T, y1T, y2T, y3T, y4T) + n0 + sgx * 16;
        uint4 a0 = *(const uint4*)pa;
        uint4 a1 = *(const uint4*)(pa + 8);
        uint4 b0 = *(const uint4*)pb;
        uint4 b1 = *(const uint4*)(pb + 8);
        const u16* wsrc = WT + (size_t)wrow * 384 + k0 + whalf * 32;
        uint4 wv[4];
        #pragma unroll
        for (int q = 0; q < 4; ++q) wv[q] = *(const uint4*)(wsrc + q * 8);

        u32 w[16];
        ilv(a0, b0, w);
        ilv(a1, b1, w + 8);
        __syncthreads();                          // prev tile reads done
        u32* xdst = &Xs[kp * 132 + sgx * 16];
        #pragma unroll
        for (int q = 0; q < 4; ++q) *(uint4*)(xdst + q * 4) = *(uint4*)(w + q * 4);
        uint4* wdst = (uint4*)&Ws[wrow * 72 + whalf * 32];
        #pragma unroll
        for (int q = 0; q < 4; ++q) wdst[q] = wv[q];
        __syncthreads();

        #pragma unroll
        for (int ks = 0; ks < 2; ++ks) {
            short8 af[4], bf[4];
            #pragma unroll
            for (int i = 0; i < 4; ++i)
                af[i] = *(const short8*)&Ws[(wr * 64 + i * 16 + m16) * 72 + ks * 32 + quad * 8];
            #pragma unroll
            for (int j = 0; j < 4; ++j) {
                const u32* xp = &Xs[(ks * 16 + quad * 4) * 132 + wc * 64 + j * 16 + m16];
                union { uint4 u; short8 s; } fu;
                fu.u.x = xp[0]; fu.u.y = xp[132]; fu.u.z = xp[264]; fu.u.w = xp[396];
                bf[j] = fu.s;
            }
            #pragma unroll
            for (int i = 0; i < 4; ++i)
                #pragma unroll
                for (int j = 0; j < 4; ++j)
                    acc[i][j] = __builtin_amdgcn_mfma_f32_16x16x32_bf16(af[i], bf[j], acc[i][j], 0, 0, 0);
        }
    }
    // epilogue
    #pragma unroll
    for (int i = 0; i < 4; ++i) {
        const int o0 = wr * 64 + i * 16 + quad * 4;
        floatx4 bz = *(const floatx4*)&bias[o0];
        #pragma unroll
        for (int j = 0; j < 4; ++j) {
            const int bnl = wc * 64 + j * 16 + m16;
            const size_t bn = (size_t)b * 4096 + n0 + bnl;
            floatx4 v = acc[i][j];
            float s[4];
            #pragma unroll
            for (int e = 0; e < 4; ++e) s[e] = 1.f / (1.f + __expf(-(v[e] + bz[e])));
            if (wr == 0) {          // r -> x0T state rows: bf16(r*hx)
                floatx4 hv = *(const floatx4*)&hx[bn * 64 + o0];
                #pragma unroll
                for (int e = 0; e < 4; ++e)
                    x0Tw[(size_t)((o0 + e + 2) * 64 + b) * 4096 + (n0 + bnl)] = f2b(s[e] * hv[e]);
            } else {                // u -> u_t[bn][o-64]
                u16x4 pk;
                #pragma unroll
                for (int e = 0; e < 4; ++e) pk[e] = f2b(s[e]);
                *(u16x4*)&u_t[bn * 64 + (o0 - 64)] = pk;
            }
        }
    }
}

// --------------------------------------- proj g: MFMA GEMM + tanh + GRU output
__global__ __launch_bounds__(256, 2) void proj_g_kernel(
        const u16* __restrict__ x0T, const u16* __restrict__ y1T,
        const u16* __restrict__ y2T, const u16* __restrict__ y3T,
        const u16* __restrict__ y4T,
        const u16* __restrict__ WT, const float* __restrict__ bias,
        const float* __restrict__ hx, const u16* __restrict__ u_t,
        float* __restrict__ out) {
    __shared__ __align__(16) u32 Xs[32 * 132];
    __shared__ __align__(16) u16 Ws[64 * 72];
    const int t = threadIdx.x;
    const int lane = t & 63, wave = t >> 6;
    const int m16 = lane & 15, quad = lane >> 4;
    const int wr = wave >> 1, wc = wave & 1;
    const int n0 = blockIdx.x * 128, b = blockIdx.y;

    const int kp = t >> 3, sgx = t & 7;
    const int wrow = t >> 2, wq = t & 3;

    floatx4 acc[2][4];
    #pragma unroll
    for (int i = 0; i < 2; ++i)
        #pragma unroll
        for (int j = 0; j < 4; ++j) acc[i][j] = (floatx4)0.f;

    for (int ki = 0; ki < 6; ++ki) {
        const int k0 = ki * 64;
        const u16* pa = xrow(k0 + 2 * kp,     b, x0T, y1T, y2T, y3T, y4T) + n0 + sgx * 16;
        const u16* pb = xrow(k0 + 2 * kp + 1, b, x0T, y1T, y2T, y3T, y4T) + n0 + sgx * 16;
        uint4 a0 = *(const uint4*)pa;
        uint4 a1 = *(const uint4*)(pa + 8);
        uint4 b0 = *(const uint4*)pb;
        uint4 b1 = *(const uint4*)(pb + 8);
        const u16* wsrc = WT + (size_t)wrow * 384 + k0 + wq * 16;
        uint4 w0 = *(const uint4*)wsrc;
        uint4 w1 = *(const uint4*)(wsrc + 8);

        u32 w[16];
        ilv(a0, b0, w);
        ilv(a1, b1, w + 8);
        __syncthreads();
        u32* xdst = &Xs[kp * 132 + sgx * 16];
        #pragma unroll
        for (int q = 0; q < 4; ++q) *(uint4*)(xdst + q * 4) = *(uint4*)(w + q * 4);
        *(uint4*)&Ws[wrow * 72 + wq * 16] = w0;
        *(uint4*)&Ws[wrow * 72 + wq * 16 + 8] = w1;
        __syncthreads();

        #pragma unroll
        for (int ks = 0; ks < 2; ++ks) {
            short8 af[2], bf[4];
            #pragma unroll
            for (int i = 0; i < 2; ++i)
                af[i] = *(const short8*)&Ws[(wr * 32 + i * 16 + m16) * 72 + ks * 32 + quad * 8];
            #pragma unroll
            for (int j = 0; j < 4; ++j) {
                const u32* xp = &Xs[(ks * 16 + quad * 4) * 132 + wc * 64 + j * 16 + m16];
                union { uint4 u; short8 s; } fu;
                fu.u.x = xp[0]; fu.u.y = xp[132]; fu.u.z = xp[264]; fu.u.w = xp[396];
                bf[j] = fu.s;
            }
            #pragma unroll
            for (int i = 0; i < 2; ++i)
                #pragma unroll
                for (int j = 0; j < 4; ++j)
                    acc[i][j] = __builtin_amdgcn_mfma_f32_16x16x32_bf16(af[i], bf[j], acc[i][j], 0, 0, 0);
        }
    }
    #pragma unroll
    for (int i = 0; i < 2; ++i) {
        const int o0 = wr * 32 + i * 16 + quad * 4;
        floatx4 bz = *(const floatx4*)&bias[o0];
        #pragma unroll
        for (int j = 0; j < 4; ++j) {
            const int bnl = wc * 64 + j * 16 + m16;
            const size_t bn = (size_t)b * 4096 + n0 + bnl;
            floatx4 v = acc[i][j];
            u16x4 uu = *(const u16x4*)&u_t[bn * 64 + o0];
            floatx4 hv = *(const floatx4*)&hx[bn * 64 + o0];
            floatx4 ov;
            #pragma unroll
            for (int e = 0; e < 4; ++e) {
                float c = tanhf(v[e] + bz[e]);
                float u = b2f(uu[e]);
                ov[e] = u * hv[e] + (1.f - u) * c;
            }
            *(floatx4*)&out[bn * 64 + o0] = ov;
        }
    }
}

// --------------------------------------------------------------------- launch
extern "C" void kernel_launch(void* const* d_in, const int* in_sizes, int n_in,
                              void* d_out, int out_size, void* d_ws, size_t ws_size,
                              hipStream_t stream) {
    (void)in_sizes; (void)n_in; (void)out_size; (void)ws_size;
    const float* inputs   = (const float*)d_in[0];
    const float* hx       = (const float*)d_in[1];
    const float* supports = (const float*)d_in[2];
    const float* w_fn     = (const float*)d_in[3];
    const float* b_fn     = (const float*)d_in[4];
    const float* w_g      = (const float*)d_in[5];
    const float* b_g      = (const float*)d_in[6];
    float* out = (float*)d_out;

    const size_t NN = (size_t)4096 * 4096;
    const size_t XT = (size_t)4224 * 4096;
    u16* Sb  = (u16*)d_ws;                      // 67.1 MB
    u16* x0T = Sb + 2 * NN;                     // 34.6 MB each
    u16* y1T = x0T + XT;
    u16* y2T = y1T + XT;
    u16* y3T = y2T + XT;
    u16* y4T = y3T + XT;
    u16* u_t = y4T + XT;                        // [bn][o'] bf16, 33.6 MB
    u16* WT_fn = u_t + (size_t)262144 * 64;     // 128*384 u16
    u16* WT_g  = WT_fn + 128 * 384;             // 64*384 u16
    u16* S0b = Sb;
    u16* S1b = Sb + NN;

    const dim3 gg(32, 33);

    cvt_bf16_kernel<<<32768, 256, 0, stream>>>(supports, Sb);
    build_x0_inputs<<<128, 256, 0, stream>>>(inputs, x0T);
    build_x0_state<<<dim3(64, 64), 256, 0, stream>>>(hx, x0T);
    wt_prep<<<192, 256, 0, stream>>>(w_fn, WT_fn, 128);
    wt_prep<<<96, 256, 0, stream>>>(w_g, WT_g, 64);
    // gconv fn diffusion
    gemm_kernel<0><<<gg, 256, 0, stream>>>(S0b, x0T, y1T, nullptr);
    gemm_kernel<1><<<gg, 256, 0, stream>>>(S0b, y1T, y2T, x0T);
    gemm_kernel<0><<<gg, 256, 0, stream>>>(S1b, y1T, y3T, nullptr);
    gemm_kernel<1><<<gg, 256, 0, stream>>>(S1b, y3T, y4T, y1T);
    // r,u gates (MFMA): r*hx into x0T state rows, u into u_t
    proj_fn_kernel<<<dim3(32, 64), 256, 0, stream>>>(x0T, y1T, y2T, y3T, y4T,
                                                     WT_fn, b_fn, hx, u_t, x0T);
    // gconv g diffusion
    gemm_kernel<0><<<gg, 256, 0, stream>>>(S0b, x0T, y1T, nullptr);
    gemm_kernel<1><<<gg, 256, 0, stream>>>(S0b, y1T, y2T, x0T);
    gemm_kernel<0><<<gg, 256, 0, stream>>>(S1b, y1T, y3T, nullptr);
    gemm_kernel<1><<<gg, 256, 0, stream>>>(S1b, y3T, y4T, y1T);
    // c = tanh(...), out = u*hx + (1-u)*c
    proj_g_kernel<<<dim3(32, 64), 256, 0, stream>>>(x0T, y1T, y2T, y3T, y4T,
                                                    WT_g, b_g, hx, u_t, out);
}